// Round 3
// baseline (137.145 us; speedup 1.0000x reference)
//
#include <hip/hip_runtime.h>
#include <hip/hip_bf16.h>

// AttnPredictor round 21: r20 + kB batch-tile BQ 16 -> 32 (512 blocks).
// kB's dominant remaining term is L2 traffic: M[h] (128 KB) is read once
// per block regardless of batch count -> 1024 blocks = 128 MB of M reads
// (~3.7us at L2 BW) + 64 MB U2 + ~20 MB W1g. Doubling batches/block
// halves all of it (96 MB total). Total VALU unchanged (2x per-thread,
// 0.5x blocks); 2 blocks/CU = 8 waves/CU; LDS ~24 KB; MFMA gains a
// second m-tile (rows 16-31) mirroring the verified 16-row structure.
//  kA (512 blocks):
//   [0,64)    P1: w = softmax_d(z*(a@Wqk + bqk)/sqrt192), attn_weights
//   [64,224)  U2[h,d/2,k] = half2{U[d],U[d+1]}, U = Wfv·W1 ; dt==4: c0'
//   [224,480) M_s (MFMA, 8 blocks/h, B-frags direct-global); kt==0: c1
//   [480,512) W1g'[h][20][256] (rows 18,19 zero)
//  kB (512 blocks, XCD-swizzled h, 32 b per block):
//   g(regs, rank-18) -> P via pk_f16/fdot2 -> relu(P@M+c1)·W2o+b2o (MFMA)

typedef __attribute__((ext_vector_type(8))) short bf16x8;
typedef __attribute__((ext_vector_type(4))) short bf16x4;
typedef __attribute__((ext_vector_type(4))) float f32x4;
typedef _Float16 half2v __attribute__((ext_vector_type(2)));
typedef __attribute__((ext_vector_type(4))) unsigned uint4v;

__device__ __forceinline__ short f2bf(float x) {
  unsigned u = __float_as_uint(x);
  u += 0x7fffu + ((u >> 16) & 1u);          // round-to-nearest-even
  return (short)(u >> 16);
}
__device__ __forceinline__ float bf2f(unsigned short u) {
  return __uint_as_float((unsigned)u << 16);
}
__device__ __forceinline__ unsigned h2u(half2v h) {
  union { half2v h; unsigned u; } c; c.h = h; return c.u;
}
__device__ __forceinline__ half2v u2h(unsigned u) {
  union { unsigned u; half2v h; } c; c.u = u; return c.h;
}
__device__ __forceinline__ float dot2acc(half2v a, half2v b, float c) {
#if __has_builtin(__builtin_amdgcn_fdot2)
  return __builtin_amdgcn_fdot2(a, b, c, false);
#else
  float r;
  asm("v_dot2_f32_f16 %0, %1, %2, %3" : "=v"(r) : "v"(a), "v"(b), "v"(c));
  return r;
#endif
}

__global__ __launch_bounds__(256) void kA_prep(
    const float* __restrict__ feat, const float* __restrict__ act,
    const float* __restrict__ Wq, const float* __restrict__ bq,
    const float* __restrict__ Wk,
    const float* __restrict__ Wav, const float* __restrict__ bav,
    const float* __restrict__ Wfv, const float* __restrict__ bfv,
    const float* __restrict__ W1, const float* __restrict__ b1,
    const float* __restrict__ W2, const float* __restrict__ b2,
    const float* __restrict__ W1o, const float* __restrict__ b1o,
    float* __restrict__ ws_w, unsigned* __restrict__ ws_U2,
    float* __restrict__ ws_c0, unsigned short* __restrict__ ws_Mbf,
    float* __restrict__ ws_c1, float* __restrict__ ws_W1g,
    float* __restrict__ out_aw) {
  __shared__ __align__(16) char smem[28800];  // aliased per range
  float* sh = (float*)smem;
  const int bx = blockIdx.x;
  const int t = threadIdx.x;

  if (bx < 64) {
    // ---------------- P1: softmax weights + attn_weights (8 b per block)
    const int b0 = bx * 8;
    float* sWk = sh;                        // [192 c][32 d] transposed
    float* sA  = sh + 6144;                 // act [8][18]
    float* sQk = sh + 6320;                 // [19 j][32 d] (row 18 = bq row)
    float* sW  = sh + 6944;                 // [8][32]
#pragma unroll
    for (int i = 0; i < 24; ++i) {
      const int idx = i * 256 + t;          // idx = d*192 + c
      sWk[(idx % 192) * 32 + (idx / 192)] = Wk[idx];
    }
    if (t < 144) sA[t] = act[b0 * 18 + t];
    __syncthreads();
    for (int o = t; o < 608; o += 256) {    // Wqk[j][d]; j==18 -> bqk
      const int j = o >> 5, d = o & 31;
      const float* arow = (j < 18) ? (Wq + j * 192) : bq;
      float acc = 0.f;
      for (int c = 0; c < 192; ++c) acc += arow[c] * sWk[c * 32 + d];
      sQk[o] = acc;
    }
    __syncthreads();
    {
      const int bi = t >> 5, d = t & 31;
      float dot = sQk[18 * 32 + d];
#pragma unroll
      for (int j = 0; j < 18; ++j) dot += sA[bi * 18 + j] * sQk[j * 32 + d];
      const float z = feat[b0 * 32 + t];
      float sc = z * dot * 0.07216878364870322f;   // 1/sqrt(192)
      float mx = sc;
#pragma unroll
      for (int off = 16; off >= 1; off >>= 1) mx = fmaxf(mx, __shfl_xor(mx, off, 64));
      const float e = __expf(sc - mx);
      float s = e;
#pragma unroll
      for (int off = 16; off >= 1; off >>= 1) s += __shfl_xor(s, off, 64);
      const float w = e / s;
      ws_w[b0 * 32 + t] = w;
      sW[t] = w;
    }
    __syncthreads();
#pragma unroll
    for (int i = 0; i < 32; ++i)
      out_aw[b0 * 1024 + i * 256 + t] = sW[(i >> 2) * 32 + (t & 31)];

  } else if (bx < 224) {
    // ---------------- U range: 5 blocks per h (dt<4: 8 d's; dt==4: c0')
    const int r = bx - 64;
    const int h = r / 5, dt = r % 5;
    float* sF = sh;                         // [8][128] Wfv tile (or bfv)
    if (dt < 4) {
#pragma unroll
      for (int i = 0; i < 4; ++i) sF[i * 256 + t] = Wfv[dt * 1024 + i * 256 + t];
    } else {
      if (t < 128) sF[t] = bfv[t];
    }
    __syncthreads();
    if (dt < 4) {
      float acc[8];
#pragma unroll
      for (int dd = 0; dd < 8; ++dd) acc[dd] = 0.f;
#pragma unroll 4
      for (int fc = 0; fc < 32; ++fc) {
        float w1v[4];
#pragma unroll
        for (int u = 0; u < 4; ++u) w1v[u] = W1[(h * 192 + fc * 4 + u) * 256 + t];
#pragma unroll
        for (int dd = 0; dd < 8; ++dd) {
          float4 f4 = *(const float4*)(sF + dd * 128 + fc * 4);
          acc[dd] += f4.x * w1v[0] + f4.y * w1v[1] + f4.z * w1v[2] + f4.w * w1v[3];
        }
      }
      // pack d-pairs as half2 (RNE): ws_U2[h][dt*4+i][k=t]
#pragma unroll
      for (int i = 0; i < 4; ++i) {
        half2v p;
        p[0] = (_Float16)acc[2 * i];
        p[1] = (_Float16)acc[2 * i + 1];
        ws_U2[(h * 16 + dt * 4 + i) * 256 + t] = h2u(p);
      }
    } else {
      float acc = b1[h * 256 + t];
      for (int fc = 0; fc < 32; ++fc) {
        float w1v[4];
#pragma unroll
        for (int u = 0; u < 4; ++u) w1v[u] = W1[(h * 192 + fc * 4 + u) * 256 + t];
        float4 f4 = *(const float4*)(sF + fc * 4);
        acc += f4.x * w1v[0] + f4.y * w1v[1] + f4.z * w1v[2] + f4.w * w1v[3];
      }
      // fold bav·W1[h,128:192,k] into c0 (bav[u] uniform -> s_load)
      for (int u = 0; u < 64; ++u)
        acc += bav[u] * W1[(h * 192 + 128 + u) * 256 + t];
      ws_c0[h * 256 + t] = acc;
    }

  } else if (bx < 480) {
    // ---------------- M range (MFMA): 8 blocks/h, 32 k1-rows each (kc = kt).
    // A (W2 tile) staged in LDS once; B-fragments (W1o) loaded directly
    // from global per lane (8x stride-1KB f32 -> f2bf pack). No barriers
    // after the single A-stage sync; all loads independent.
    const int r = bx - 224;
    const int h = r >> 3, kt = r & 7;
    short* sW2 = (short*)smem;              // [32][206] bf16 A-tile

    for (int i = t; i < 6144; i += 256) {
      const int row = i / 192, col = i - row * 192;
      sW2[row * 206 + col] = f2bf(W2[h * 49152 + (kt * 32 + row) * 192 + col]);
    }
    const int wv = t >> 6, lane = t & 63;
    const int quad = lane >> 4, l15 = lane & 15;

    f32x4 acc[2][4];
    const f32x4 zero = {0.f, 0.f, 0.f, 0.f};
#pragma unroll
    for (int mt = 0; mt < 2; ++mt)
#pragma unroll
      for (int nt = 0; nt < 4; ++nt) acc[mt][nt] = zero;

    __syncthreads();

    const float* W1oh = W1o + h * 49152;
#pragma unroll
    for (int kk = 0; kk < 6; ++kk) {
      bf16x8 a0[2];
#pragma unroll
      for (int mt = 0; mt < 2; ++mt)
        a0[mt] = *(const bf16x8*)(sW2 + (mt * 16 + l15) * 206 + kk * 32 + quad * 8);
#pragma unroll
      for (int nt = 0; nt < 4; ++nt) {
        const int col = wv * 64 + nt * 16 + l15;
        const float* src = W1oh + (kk * 32 + quad * 8) * 256 + col;
        bf16x8 b0;
#pragma unroll
        for (int j = 0; j < 8; ++j) b0[j] = f2bf(src[j * 256]);
#pragma unroll
        for (int mt = 0; mt < 2; ++mt)
          acc[mt][nt] = __builtin_amdgcn_mfma_f32_16x16x32_bf16(a0[mt], b0, acc[mt][nt], 0, 0, 0);
      }
    }
    // store fragment-order: M_s[h][kc=kt][col][k1&31], k1&31 = mt*16+quad*4+r
#pragma unroll
    for (int mt = 0; mt < 2; ++mt) {
#pragma unroll
      for (int nt = 0; nt < 4; ++nt) {
        const int col = wv * 64 + nt * 16 + l15;
        const unsigned p0 = ((unsigned)(unsigned short)f2bf(acc[mt][nt][1]) << 16) |
                            (unsigned short)f2bf(acc[mt][nt][0]);
        const unsigned p1 = ((unsigned)(unsigned short)f2bf(acc[mt][nt][3]) << 16) |
                            (unsigned short)f2bf(acc[mt][nt][2]);
        unsigned* dst = (unsigned*)(ws_Mbf + ((size_t)(h * 8 + kt) * 256 + col) * 32 +
                                    mt * 16 + quad * 4);
        dst[0] = p0; dst[1] = p1;
      }
    }
    if (kt == 0) {
      float c1acc = b1o[h * 256 + t];
      for (int v = 0; v < 192; ++v)
        c1acc += b2[h * 192 + v] * W1oh[v * 256 + t];
      ws_c1[h * 256 + t] = c1acc;
    }

  } else {
    // ---------------- W1g' range: 1 block per h.
    const int h = bx - 480;
    float accj[18];
#pragma unroll
    for (int j = 0; j < 18; ++j) accj[j] = 0.f;
#pragma unroll 4
    for (int u = 0; u < 64; ++u) {
      const float w1v = W1[(h * 192 + 128 + u) * 256 + t];
#pragma unroll
      for (int j = 0; j < 18; ++j)
        accj[j] += Wav[j * 64 + u] * w1v;
    }
#pragma unroll
    for (int j = 0; j < 18; ++j)
      ws_W1g[(h * 20 + j) * 256 + t] = accj[j];
    ws_W1g[(h * 20 + 18) * 256 + t] = 0.f;
    ws_W1g[(h * 20 + 19) * 256 + t] = 0.f;
  }
}

// ---------------------------------------------------------------- kB: G(regs, rank-18)+P (pk-f16) -> MFMA -> effect
// 512 blocks, 32 batches each. Thread: bq = t>>6 -> rows bq*8..+8,
// kg = t&63 -> cols kg*4..+4.
__global__ __launch_bounds__(256) void kB_main(
    const float* __restrict__ feat, const float* __restrict__ act,
    const float* __restrict__ ws_w, const unsigned* __restrict__ ws_U2,
    const float* __restrict__ ws_W1g, const float* __restrict__ ws_c0,
    const unsigned short* __restrict__ ws_Mbf, const float* __restrict__ ws_c1,
    const float* __restrict__ W2o, const float* __restrict__ b2o,
    float* __restrict__ out_eff) {
  const int bx = blockIdx.x;
  const int h = (bx & 7) * 4 + ((bx >> 3) & 3);   // XCD swizzle (bijective in bx&31)
  const int bt = bx >> 5;                   // 32 b per block
  const int b0 = bt * 32;
  const int t = threadIdx.x;

  __shared__ __align__(16) char smem[24064];
  short* sP     = (short*)smem;             // [32][264] bf16 : 16896 B
  float* sA     = (float*)(smem + 16896);   // [32][20] act, cols 18-19 zero
  unsigned* sZ2 = (unsigned*)(smem + 19456);// [32][16] half2{z2dp,z2dp+1}
  unsigned* sWp = (unsigned*)(smem + 21504);// [32][16] half2{w2dp,w2dp+1}
  float* sRed   = (float*)(smem + 23552);   // [32][4]

  // ---- stage act (zero-padded), z/w as half2 d-pairs into LDS
  {
    const int dp = t & 15;
#pragma unroll
    for (int i = 0; i < 2; ++i) {
      const int bb = i * 16 + (t >> 4);
      float2 zv = *(const float2*)(feat + (b0 + bb) * 32 + 2 * dp);
      float2 wv = *(const float2*)(ws_w + (b0 + bb) * 32 + 2 * dp);
      half2v zp; zp[0] = (_Float16)zv.x; zp[1] = (_Float16)zv.y;
      half2v wp; wp[0] = (_Float16)wv.x; wp[1] = (_Float16)wv.y;
      sZ2[bb * 16 + dp] = h2u(zp);
      sWp[bb * 16 + dp] = h2u(wp);
    }
    for (int i = t; i < 640; i += 256) {
      const int row = i / 20, col = i - row * 20;
      sA[i] = (col < 18) ? act[(b0 + row) * 18 + col] : 0.f;
    }
  }
  __syncthreads();

  // ---- fused G(registers, rank-18) + P
  {
    const int bq = t >> 6, kg = t & 63;
    float g[8][4];

    // G: g[r][c] = c0'[c] + sum_{j<20} a[row][j]*W1g'[h][j][col]   (f32)
    {
      float4 c04 = *(const float4*)(ws_c0 + h * 256 + kg * 4);
#pragma unroll
      for (int r = 0; r < 8; ++r) {
        g[r][0] = c04.x; g[r][1] = c04.y; g[r][2] = c04.z; g[r][3] = c04.w;
      }
      const float* Wgp = ws_W1g + (h * 20) * 256 + kg * 4;
#pragma unroll
      for (int jc = 0; jc < 5; ++jc) {
        float w1q[4][4];
#pragma unroll
        for (int u = 0; u < 4; ++u) {
          float4 w4 = *(const float4*)(Wgp + (jc * 4 + u) * 256);
          w1q[u][0] = w4.x; w1q[u][1] = w4.y; w1q[u][2] = w4.z; w1q[u][3] = w4.w;
        }
#pragma unroll
        for (int r = 0; r < 8; ++r) {
          float4 av = *(const float4*)(sA + (bq * 8 + r) * 20 + jc * 4);
#pragma unroll
          for (int u = 0; u < 4; ++u) {
            const float a = (u == 0) ? av.x : (u == 1) ? av.y : (u == 2) ? av.z : av.w;
#pragma unroll
            for (int c = 0; c < 4; ++c)
              g[r][c] += a * w1q[u][c];
          }
        }
      }
    }

    // g -> broadcast half2 (RNE, 1 cvt each)
    half2v g2[8][4];
#pragma unroll
    for (int r = 0; r < 8; ++r)
#pragma unroll
      for (int c = 0; c < 4; ++c) {
        _Float16 gh = (_Float16)g[r][c];
        half2v gg; gg[0] = gh; gg[1] = gh;
        g2[r][c] = gg;
      }

    // P: acc[r][c] = sum_dpair fdot2(w2, pk_max(pk_fma(z2, U2, g2), 0))
    float acc[8][4];
#pragma unroll
    for (int r = 0; r < 8; ++r)
#pragma unroll
      for (int c = 0; c < 4; ++c) acc[r][c] = 0.f;
    const half2v hzero = {(_Float16)0.f, (_Float16)0.f};
    const unsigned* Up = ws_U2 + h * 4096 + kg * 4;
#pragma unroll
    for (int dc = 0; dc < 8; ++dc) {
      uint4v ua = *(const uint4v*)(Up + (2 * dc) * 256);      // dpair 2dc
      uint4v ub = *(const uint4v*)(Up + (2 * dc + 1) * 256);  // dpair 2dc+1
#pragma unroll
      for (int r = 0; r < 8; ++r) {
        uint2 zz = *(const uint2*)(sZ2 + (bq * 8 + r) * 16 + 2 * dc);
        uint2 ww = *(const uint2*)(sWp + (bq * 8 + r) * 16 + 2 * dc);
        const half2v z0 = u2h(zz.x), z1 = u2h(zz.y);
        const half2v w0 = u2h(ww.x), w1 = u2h(ww.y);
#pragma unroll
        for (int c = 0; c < 4; ++c) {
          half2v hA = __builtin_elementwise_fma(z0, u2h(ua[c]), g2[r][c]);
          hA = __builtin_elementwise_max(hA, hzero);
          acc[r][c] = dot2acc(w0, hA, acc[r][c]);
          half2v hB = __builtin_elementwise_fma(z1, u2h(ub[c]), g2[r][c]);
          hB = __builtin_elementwise_max(hB, hzero);
          acc[r][c] = dot2acc(w1, hB, acc[r][c]);
        }
      }
    }
#pragma unroll
    for (int r = 0; r < 8; ++r) {
      bf16x4 p;
#pragma unroll
      for (int c = 0; c < 4; ++c) p[c] = f2bf(acc[r][c]);
      *(bf16x4*)(sP + (bq * 8 + r) * 264 + kg * 4) = p;
    }
  }
  __syncthreads();

  // ---- MFMA: D[32 b][64 k2 per wave] = P @ M ; epilogue
  // M_s[h][kc][col][k1&31]: wave load at (kc,nt) is 1 KB contiguous.
  {
    const int wv = t >> 6;
    const int lane = t & 63;
    const int quad = lane >> 4, l15 = lane & 15;

    f32x4 acc[2][4];
    const f32x4 zero = {0.f, 0.f, 0.f, 0.f};
#pragma unroll
    for (int mt = 0; mt < 2; ++mt)
#pragma unroll
      for (int nt = 0; nt < 4; ++nt) acc[mt][nt] = zero;

    float c1r[4], w2r[4];
#pragma unroll
    for (int nt = 0; nt < 4; ++nt) {
      const int col = wv * 64 + nt * 16 + l15;
      c1r[nt] = ws_c1[h * 256 + col];
      w2r[nt] = W2o[h * 256 + col];
    }
    const unsigned short* Mh = ws_Mbf + (size_t)h * 8 * 256 * 32;

#pragma unroll
    for (int kc = 0; kc < 8; ++kc) {
      bf16x8 a0[2];
#pragma unroll
      for (int mt = 0; mt < 2; ++mt)
        a0[mt] = *(const bf16x8*)(sP + (mt * 16 + l15) * 264 + kc * 32 + quad * 8);
      const unsigned short* Mk = Mh + (size_t)kc * 8192 + (wv * 64) * 32;
      bf16x8 bfr[4];
#pragma unroll
      for (int nt = 0; nt < 4; ++nt)
        bfr[nt] = *(const bf16x8*)(Mk + (nt * 16 + l15) * 32 + quad * 8);
#pragma unroll
      for (int nt = 0; nt < 4; ++nt)
#pragma unroll
        for (int mt = 0; mt < 2; ++mt)
          acc[mt][nt] = __builtin_amdgcn_mfma_f32_16x16x32_bf16(a0[mt], bfr[nt], acc[mt][nt], 0, 0, 0);
    }
#pragma unroll
    for (int mt = 0; mt < 2; ++mt) {
#pragma unroll
      for (int r = 0; r < 4; ++r) {
        float s = fmaxf(acc[mt][0][r] + c1r[0], 0.f) * w2r[0]
                + fmaxf(acc[mt][1][r] + c1r[1], 0.f) * w2r[1]
                + fmaxf(acc[mt][2][r] + c1r[2], 0.f) * w2r[2]
                + fmaxf(acc[mt][3][r] + c1r[3], 0.f) * w2r[3];
        s += __shfl_xor(s, 1, 64);
        s += __shfl_xor(s, 2, 64);
        s += __shfl_xor(s, 4, 64);
        s += __shfl_xor(s, 8, 64);
        if (l15 == 0) sRed[(mt * 16 + quad * 4 + r) * 4 + wv] = s;
      }
    }
  }
  __syncthreads();
  if (t < 32) {
    float v = sRed[t * 4] + sRed[t * 4 + 1] + sRed[t * 4 + 2] + sRed[t * 4 + 3] + b2o[h];
    out_eff[(b0 + t) * 32 + h] = v;
  }
}

// ----------------------------------------------------------------
extern "C" void kernel_launch(void* const* d_in, const int* in_sizes, int n_in,
                              void* d_out, int out_size, void* d_ws, size_t ws_size,
                              hipStream_t stream) {
  const float* feat = (const float*)d_in[0];
  const float* act  = (const float*)d_in[1];
  const float* Wq   = (const float*)d_in[2];
  const float* bq   = (const float*)d_in[3];
  const float* Wk   = (const float*)d_in[4];
  // d_in[5] = bk: cancels in softmax
  const float* Wav  = (const float*)d_in[6];
  const float* bav  = (const float*)d_in[7];
  const float* Wfv  = (const float*)d_in[8];
  const float* bfv  = (const float*)d_in[9];
  const float* W1   = (const float*)d_in[10];
  const float* b1   = (const float*)d_in[11];
  const float* W2   = (const float*)d_in[12];
  const float* b2   = (const float*)d_in[13];
  const float* W1o  = (const float*)d_in[14];
  const float* b1o  = (const float*)d_in[15];
  const float* W2o  = (const float*)d_in[16];
  const float* b2o  = (const float*)d_in[17];
  float* out = (float*)d_out;               // [0,16384): effect; rest: attn_weights
  float* ws = (float*)d_ws;

  float* ws_w  = ws;                                        // 16384
  unsigned* ws_U2 = (unsigned*)(ws + 16384);                // 131072 uints (512KB)
  float* ws_c0 = ws + 278528;                               // 8192
  float* ws_c1 = ws + 286720;                               // 8192
  unsigned short* ws_Mbf = (unsigned short*)(ws + 294912);  // 2097152 shorts
  float* ws_W1g = ws + 1343488;                             // 163840

  hipLaunchKernelGGL(kA_prep, dim3(512), dim3(256), 0, stream,
                     feat, act, Wq, bq, Wk, Wav, bav, Wfv, bfv, W1, b1,
                     W2, b2, W1o, b1o, ws_w, ws_U2, ws_c0, ws_Mbf, ws_c1,
                     ws_W1g, out + 16384);
  hipLaunchKernelGGL(kB_main, dim3(512), dim3(256), 0, stream,
                     feat, act, ws_w, ws_U2, ws_W1g, ws_c0, ws_Mbf, ws_c1,
                     W2o, b2o, out);
}

// Round 4
// 133.258 us; speedup vs baseline: 1.0292x; 1.0292x over previous
//
#include <hip/hip_runtime.h>
#include <hip/hip_bf16.h>

// AttnPredictor round 22: revert r21 (BQ=32 regressed: kB is VALU/issue
// bound, not L2-BW bound; halving blocks cost occupancy) back to r20's
// BQ=16 / 1024-block kB, plus one safe tweak: hoist kB's c1r/w2r epilogue
// loads to kernel entry so their L2 latency hides under the G/P phases
// instead of sitting on the post-barrier critical path.
//  kA (512 blocks):
//   [0,64)    P1: w = softmax_d(z*(a@Wqk + bqk)/sqrt192), attn_weights
//   [64,224)  U2[h,d/2,k] = half2{U[d],U[d+1]}, U = Wfv·W1 ; dt==4: c0'
//   [224,480) M_s (MFMA, 8 blocks/h, B-frags direct-global); kt==0: c1
//   [480,512) W1g'[h][20][256] (rows 18,19 zero)
//  kB (1024 blocks, XCD-swizzled h, 16 b per block):
//   g(regs, rank-18) -> P via pk_f16/fdot2 -> relu(P@M+c1)·W2o+b2o (MFMA)

typedef __attribute__((ext_vector_type(8))) short bf16x8;
typedef __attribute__((ext_vector_type(4))) short bf16x4;
typedef __attribute__((ext_vector_type(4))) float f32x4;
typedef _Float16 half2v __attribute__((ext_vector_type(2)));
typedef __attribute__((ext_vector_type(4))) unsigned uint4v;

__device__ __forceinline__ short f2bf(float x) {
  unsigned u = __float_as_uint(x);
  u += 0x7fffu + ((u >> 16) & 1u);          // round-to-nearest-even
  return (short)(u >> 16);
}
__device__ __forceinline__ float bf2f(unsigned short u) {
  return __uint_as_float((unsigned)u << 16);
}
__device__ __forceinline__ unsigned h2u(half2v h) {
  union { half2v h; unsigned u; } c; c.h = h; return c.u;
}
__device__ __forceinline__ half2v u2h(unsigned u) {
  union { unsigned u; half2v h; } c; c.u = u; return c.h;
}
__device__ __forceinline__ float dot2acc(half2v a, half2v b, float c) {
#if __has_builtin(__builtin_amdgcn_fdot2)
  return __builtin_amdgcn_fdot2(a, b, c, false);
#else
  float r;
  asm("v_dot2_f32_f16 %0, %1, %2, %3" : "=v"(r) : "v"(a), "v"(b), "v"(c));
  return r;
#endif
}

__global__ __launch_bounds__(256) void kA_prep(
    const float* __restrict__ feat, const float* __restrict__ act,
    const float* __restrict__ Wq, const float* __restrict__ bq,
    const float* __restrict__ Wk,
    const float* __restrict__ Wav, const float* __restrict__ bav,
    const float* __restrict__ Wfv, const float* __restrict__ bfv,
    const float* __restrict__ W1, const float* __restrict__ b1,
    const float* __restrict__ W2, const float* __restrict__ b2,
    const float* __restrict__ W1o, const float* __restrict__ b1o,
    float* __restrict__ ws_w, unsigned* __restrict__ ws_U2,
    float* __restrict__ ws_c0, unsigned short* __restrict__ ws_Mbf,
    float* __restrict__ ws_c1, float* __restrict__ ws_W1g,
    float* __restrict__ out_aw) {
  __shared__ __align__(16) char smem[28800];  // aliased per range
  float* sh = (float*)smem;
  const int bx = blockIdx.x;
  const int t = threadIdx.x;

  if (bx < 64) {
    // ---------------- P1: softmax weights + attn_weights (8 b per block)
    const int b0 = bx * 8;
    float* sWk = sh;                        // [192 c][32 d] transposed
    float* sA  = sh + 6144;                 // act [8][18]
    float* sQk = sh + 6320;                 // [19 j][32 d] (row 18 = bq row)
    float* sW  = sh + 6944;                 // [8][32]
#pragma unroll
    for (int i = 0; i < 24; ++i) {
      const int idx = i * 256 + t;          // idx = d*192 + c
      sWk[(idx % 192) * 32 + (idx / 192)] = Wk[idx];
    }
    if (t < 144) sA[t] = act[b0 * 18 + t];
    __syncthreads();
    for (int o = t; o < 608; o += 256) {    // Wqk[j][d]; j==18 -> bqk
      const int j = o >> 5, d = o & 31;
      const float* arow = (j < 18) ? (Wq + j * 192) : bq;
      float acc = 0.f;
      for (int c = 0; c < 192; ++c) acc += arow[c] * sWk[c * 32 + d];
      sQk[o] = acc;
    }
    __syncthreads();
    {
      const int bi = t >> 5, d = t & 31;
      float dot = sQk[18 * 32 + d];
#pragma unroll
      for (int j = 0; j < 18; ++j) dot += sA[bi * 18 + j] * sQk[j * 32 + d];
      const float z = feat[b0 * 32 + t];
      float sc = z * dot * 0.07216878364870322f;   // 1/sqrt(192)
      float mx = sc;
#pragma unroll
      for (int off = 16; off >= 1; off >>= 1) mx = fmaxf(mx, __shfl_xor(mx, off, 64));
      const float e = __expf(sc - mx);
      float s = e;
#pragma unroll
      for (int off = 16; off >= 1; off >>= 1) s += __shfl_xor(s, off, 64);
      const float w = e / s;
      ws_w[b0 * 32 + t] = w;
      sW[t] = w;
    }
    __syncthreads();
#pragma unroll
    for (int i = 0; i < 32; ++i)
      out_aw[b0 * 1024 + i * 256 + t] = sW[(i >> 2) * 32 + (t & 31)];

  } else if (bx < 224) {
    // ---------------- U range: 5 blocks per h (dt<4: 8 d's; dt==4: c0')
    const int r = bx - 64;
    const int h = r / 5, dt = r % 5;
    float* sF = sh;                         // [8][128] Wfv tile (or bfv)
    if (dt < 4) {
#pragma unroll
      for (int i = 0; i < 4; ++i) sF[i * 256 + t] = Wfv[dt * 1024 + i * 256 + t];
    } else {
      if (t < 128) sF[t] = bfv[t];
    }
    __syncthreads();
    if (dt < 4) {
      float acc[8];
#pragma unroll
      for (int dd = 0; dd < 8; ++dd) acc[dd] = 0.f;
#pragma unroll 4
      for (int fc = 0; fc < 32; ++fc) {
        float w1v[4];
#pragma unroll
        for (int u = 0; u < 4; ++u) w1v[u] = W1[(h * 192 + fc * 4 + u) * 256 + t];
#pragma unroll
        for (int dd = 0; dd < 8; ++dd) {
          float4 f4 = *(const float4*)(sF + dd * 128 + fc * 4);
          acc[dd] += f4.x * w1v[0] + f4.y * w1v[1] + f4.z * w1v[2] + f4.w * w1v[3];
        }
      }
      // pack d-pairs as half2 (RNE): ws_U2[h][dt*4+i][k=t]
#pragma unroll
      for (int i = 0; i < 4; ++i) {
        half2v p;
        p[0] = (_Float16)acc[2 * i];
        p[1] = (_Float16)acc[2 * i + 1];
        ws_U2[(h * 16 + dt * 4 + i) * 256 + t] = h2u(p);
      }
    } else {
      float acc = b1[h * 256 + t];
      for (int fc = 0; fc < 32; ++fc) {
        float w1v[4];
#pragma unroll
        for (int u = 0; u < 4; ++u) w1v[u] = W1[(h * 192 + fc * 4 + u) * 256 + t];
        float4 f4 = *(const float4*)(sF + fc * 4);
        acc += f4.x * w1v[0] + f4.y * w1v[1] + f4.z * w1v[2] + f4.w * w1v[3];
      }
      // fold bav·W1[h,128:192,k] into c0 (bav[u] uniform -> s_load)
      for (int u = 0; u < 64; ++u)
        acc += bav[u] * W1[(h * 192 + 128 + u) * 256 + t];
      ws_c0[h * 256 + t] = acc;
    }

  } else if (bx < 480) {
    // ---------------- M range (MFMA): 8 blocks/h, 32 k1-rows each (kc = kt).
    // A (W2 tile) staged in LDS once; B-fragments (W1o) loaded directly
    // from global per lane (8x stride-1KB f32 -> f2bf pack). No barriers
    // after the single A-stage sync; all loads independent.
    const int r = bx - 224;
    const int h = r >> 3, kt = r & 7;
    short* sW2 = (short*)smem;              // [32][206] bf16 A-tile

    for (int i = t; i < 6144; i += 256) {
      const int row = i / 192, col = i - row * 192;
      sW2[row * 206 + col] = f2bf(W2[h * 49152 + (kt * 32 + row) * 192 + col]);
    }
    const int wv = t >> 6, lane = t & 63;
    const int quad = lane >> 4, l15 = lane & 15;

    f32x4 acc[2][4];
    const f32x4 zero = {0.f, 0.f, 0.f, 0.f};
#pragma unroll
    for (int mt = 0; mt < 2; ++mt)
#pragma unroll
      for (int nt = 0; nt < 4; ++nt) acc[mt][nt] = zero;

    __syncthreads();

    const float* W1oh = W1o + h * 49152;
#pragma unroll
    for (int kk = 0; kk < 6; ++kk) {
      bf16x8 a0[2];
#pragma unroll
      for (int mt = 0; mt < 2; ++mt)
        a0[mt] = *(const bf16x8*)(sW2 + (mt * 16 + l15) * 206 + kk * 32 + quad * 8);
#pragma unroll
      for (int nt = 0; nt < 4; ++nt) {
        const int col = wv * 64 + nt * 16 + l15;
        const float* src = W1oh + (kk * 32 + quad * 8) * 256 + col;
        bf16x8 b0;
#pragma unroll
        for (int j = 0; j < 8; ++j) b0[j] = f2bf(src[j * 256]);
#pragma unroll
        for (int mt = 0; mt < 2; ++mt)
          acc[mt][nt] = __builtin_amdgcn_mfma_f32_16x16x32_bf16(a0[mt], b0, acc[mt][nt], 0, 0, 0);
      }
    }
    // store fragment-order: M_s[h][kc=kt][col][k1&31], k1&31 = mt*16+quad*4+r
#pragma unroll
    for (int mt = 0; mt < 2; ++mt) {
#pragma unroll
      for (int nt = 0; nt < 4; ++nt) {
        const int col = wv * 64 + nt * 16 + l15;
        const unsigned p0 = ((unsigned)(unsigned short)f2bf(acc[mt][nt][1]) << 16) |
                            (unsigned short)f2bf(acc[mt][nt][0]);
        const unsigned p1 = ((unsigned)(unsigned short)f2bf(acc[mt][nt][3]) << 16) |
                            (unsigned short)f2bf(acc[mt][nt][2]);
        unsigned* dst = (unsigned*)(ws_Mbf + ((size_t)(h * 8 + kt) * 256 + col) * 32 +
                                    mt * 16 + quad * 4);
        dst[0] = p0; dst[1] = p1;
      }
    }
    if (kt == 0) {
      float c1acc = b1o[h * 256 + t];
      for (int v = 0; v < 192; ++v)
        c1acc += b2[h * 192 + v] * W1oh[v * 256 + t];
      ws_c1[h * 256 + t] = c1acc;
    }

  } else {
    // ---------------- W1g' range: 1 block per h.
    const int h = bx - 480;
    float accj[18];
#pragma unroll
    for (int j = 0; j < 18; ++j) accj[j] = 0.f;
#pragma unroll 4
    for (int u = 0; u < 64; ++u) {
      const float w1v = W1[(h * 192 + 128 + u) * 256 + t];
#pragma unroll
      for (int j = 0; j < 18; ++j)
        accj[j] += Wav[j * 64 + u] * w1v;
    }
#pragma unroll
    for (int j = 0; j < 18; ++j)
      ws_W1g[(h * 20 + j) * 256 + t] = accj[j];
    ws_W1g[(h * 20 + 18) * 256 + t] = 0.f;
    ws_W1g[(h * 20 + 19) * 256 + t] = 0.f;
  }
}

// ---------------------------------------------------------------- kB: G(regs, rank-18)+P (pk-f16) -> MFMA -> effect
__global__ __launch_bounds__(256) void kB_main(
    const float* __restrict__ feat, const float* __restrict__ act,
    const float* __restrict__ ws_w, const unsigned* __restrict__ ws_U2,
    const float* __restrict__ ws_W1g, const float* __restrict__ ws_c0,
    const unsigned short* __restrict__ ws_Mbf, const float* __restrict__ ws_c1,
    const float* __restrict__ W2o, const float* __restrict__ b2o,
    float* __restrict__ out_eff) {
  const int bx = blockIdx.x;
  const int h = (bx & 7) * 4 + ((bx >> 3) & 3);   // XCD swizzle (bijective in bx&31)
  const int bt = bx >> 5;                   // 16 b per block
  const int b0 = bt * 16;
  const int t = threadIdx.x;

  __shared__ __align__(16) char smem[12288];
  short* sP    = (short*)smem;              // [16][264] bf16 : 8448 B
  float* sA    = (float*)(smem + 8448);     // [16][20] act, cols 18-19 zero
  unsigned* sZ2 = (unsigned*)(smem + 9728); // [16][16] half2{z2dp,z2dp+1}
  unsigned* sWp = (unsigned*)(smem + 10752);// [16][16] half2{w2dp,w2dp+1}
  float* sRed  = (float*)(smem + 11776);    // [16][4]

  // ---- hoisted epilogue loads: issue early, consume after the P barrier
  const int wv0 = t >> 6;
  const int lane0 = t & 63;
  const int quad0 = lane0 >> 4, l150 = lane0 & 15;
  float c1r[4], w2r[4];
#pragma unroll
  for (int nt = 0; nt < 4; ++nt) {
    const int col = wv0 * 64 + nt * 16 + l150;
    c1r[nt] = ws_c1[h * 256 + col];
    w2r[nt] = W2o[h * 256 + col];
  }

  // ---- stage act (zero-padded), z/w as half2 d-pairs into LDS
  {
    const int bb = t >> 4, dp = t & 15;
    float2 zv = *(const float2*)(feat + (b0 + bb) * 32 + 2 * dp);
    float2 wv = *(const float2*)(ws_w + (b0 + bb) * 32 + 2 * dp);
    half2v zp; zp[0] = (_Float16)zv.x; zp[1] = (_Float16)zv.y;
    half2v wp; wp[0] = (_Float16)wv.x; wp[1] = (_Float16)wv.y;
    sZ2[bb * 16 + dp] = h2u(zp);
    sWp[bb * 16 + dp] = h2u(wp);
    for (int i = t; i < 320; i += 256) {
      const int row = i / 20, col = i - row * 20;
      sA[i] = (col < 18) ? act[(b0 + row) * 18 + col] : 0.f;
    }
  }
  __syncthreads();

  // ---- fused G(registers, rank-18) + P: thread (bq = t>>6 -> rows bq*4..+3;
  //      kg = t&63 -> cols kg*4..+3)
  {
    const int bq = t >> 6, kg = t & 63;
    float g[4][4];

    // G: g[r][c] = c0'[c] + sum_{j<20} a[row][j]*W1g'[h][j][col]   (f32)
    {
      float4 c04 = *(const float4*)(ws_c0 + h * 256 + kg * 4);
#pragma unroll
      for (int r = 0; r < 4; ++r) {
        g[r][0] = c04.x; g[r][1] = c04.y; g[r][2] = c04.z; g[r][3] = c04.w;
      }
      const float* Wgp = ws_W1g + (h * 20) * 256 + kg * 4;
#pragma unroll
      for (int jc = 0; jc < 5; ++jc) {
        float w1q[4][4];
#pragma unroll
        for (int u = 0; u < 4; ++u) {
          float4 w4 = *(const float4*)(Wgp + (jc * 4 + u) * 256);
          w1q[u][0] = w4.x; w1q[u][1] = w4.y; w1q[u][2] = w4.z; w1q[u][3] = w4.w;
        }
        float a4[4][4];
#pragma unroll
        for (int r = 0; r < 4; ++r) {
          float4 av = *(const float4*)(sA + (bq * 4 + r) * 20 + jc * 4);
          a4[r][0] = av.x; a4[r][1] = av.y; a4[r][2] = av.z; a4[r][3] = av.w;
        }
#pragma unroll
        for (int u = 0; u < 4; ++u)
#pragma unroll
          for (int r = 0; r < 4; ++r)
#pragma unroll
            for (int c = 0; c < 4; ++c)
              g[r][c] += a4[r][u] * w1q[u][c];
      }
    }

    // g -> broadcast half2 (RNE, 1 cvt each; compiler dups lanes)
    half2v g2[4][4];
#pragma unroll
    for (int r = 0; r < 4; ++r)
#pragma unroll
      for (int c = 0; c < 4; ++c) {
        _Float16 gh = (_Float16)g[r][c];
        half2v gg; gg[0] = gh; gg[1] = gh;
        g2[r][c] = gg;
      }

    // P: acc[r][c] = sum_dpair fdot2(w2, pk_max(pk_fma(z2, U2, g2), 0))
    float acc[4][4];
#pragma unroll
    for (int r = 0; r < 4; ++r) {
      acc[r][0] = 0.f; acc[r][1] = 0.f; acc[r][2] = 0.f; acc[r][3] = 0.f;
    }
    const half2v hzero = {(_Float16)0.f, (_Float16)0.f};
    const unsigned* Up = ws_U2 + h * 4096 + kg * 4;
#pragma unroll
    for (int dc = 0; dc < 8; ++dc) {
      uint4v ua = *(const uint4v*)(Up + (2 * dc) * 256);      // dpair 2dc
      uint4v ub = *(const uint4v*)(Up + (2 * dc + 1) * 256);  // dpair 2dc+1
#pragma unroll
      for (int r = 0; r < 4; ++r) {
        uint2 zz = *(const uint2*)(sZ2 + (bq * 4 + r) * 16 + 2 * dc);
        uint2 ww = *(const uint2*)(sWp + (bq * 4 + r) * 16 + 2 * dc);
        const half2v z0 = u2h(zz.x), z1 = u2h(zz.y);
        const half2v w0 = u2h(ww.x), w1 = u2h(ww.y);
#pragma unroll
        for (int c = 0; c < 4; ++c) {
          half2v hA = __builtin_elementwise_fma(z0, u2h(ua[c]), g2[r][c]);
          hA = __builtin_elementwise_max(hA, hzero);
          acc[r][c] = dot2acc(w0, hA, acc[r][c]);
          half2v hB = __builtin_elementwise_fma(z1, u2h(ub[c]), g2[r][c]);
          hB = __builtin_elementwise_max(hB, hzero);
          acc[r][c] = dot2acc(w1, hB, acc[r][c]);
        }
      }
    }
#pragma unroll
    for (int r = 0; r < 4; ++r) {
      bf16x4 p;
#pragma unroll
      for (int c = 0; c < 4; ++c) p[c] = f2bf(acc[r][c]);
      *(bf16x4*)(sP + (bq * 4 + r) * 264 + kg * 4) = p;
    }
  }
  __syncthreads();

  // ---- MFMA: D[16 b][64 k2 per wave] = P @ M ; epilogue
  // M_s[h][kc][col][k1&31]: wave load at (kc,nt) is 1 KB contiguous.
  {
    const int wv = wv0;
    const int quad = quad0, l15 = l150;

    f32x4 acc[4];
    const f32x4 zero = {0.f, 0.f, 0.f, 0.f};
#pragma unroll
    for (int nt = 0; nt < 4; ++nt) acc[nt] = zero;

    const unsigned short* Mh = ws_Mbf + (size_t)h * 8 * 256 * 32;

#pragma unroll
    for (int kc = 0; kc < 8; ++kc) {
      bf16x8 a0 = *(const bf16x8*)(sP + l15 * 264 + kc * 32 + quad * 8);
      const unsigned short* Mk = Mh + (size_t)kc * 8192 + (wv * 64) * 32;
      bf16x8 bfr[4];
#pragma unroll
      for (int nt = 0; nt < 4; ++nt)
        bfr[nt] = *(const bf16x8*)(Mk + (nt * 16 + l15) * 32 + quad * 8);
#pragma unroll
      for (int nt = 0; nt < 4; ++nt)
        acc[nt] = __builtin_amdgcn_mfma_f32_16x16x32_bf16(a0, bfr[nt], acc[nt], 0, 0, 0);
    }
#pragma unroll
    for (int r = 0; r < 4; ++r) {
      float s = fmaxf(acc[0][r] + c1r[0], 0.f) * w2r[0]
              + fmaxf(acc[1][r] + c1r[1], 0.f) * w2r[1]
              + fmaxf(acc[2][r] + c1r[2], 0.f) * w2r[2]
              + fmaxf(acc[3][r] + c1r[3], 0.f) * w2r[3];
      s += __shfl_xor(s, 1, 64);
      s += __shfl_xor(s, 2, 64);
      s += __shfl_xor(s, 4, 64);
      s += __shfl_xor(s, 8, 64);
      if (l15 == 0) sRed[(quad * 4 + r) * 4 + wv] = s;
    }
  }
  __syncthreads();
  if (t < 16) {
    float v = sRed[t * 4] + sRed[t * 4 + 1] + sRed[t * 4 + 2] + sRed[t * 4 + 3] + b2o[h];
    out_eff[(b0 + t) * 32 + h] = v;
  }
}

// ----------------------------------------------------------------
extern "C" void kernel_launch(void* const* d_in, const int* in_sizes, int n_in,
                              void* d_out, int out_size, void* d_ws, size_t ws_size,
                              hipStream_t stream) {
  const float* feat = (const float*)d_in[0];
  const float* act  = (const float*)d_in[1];
  const float* Wq   = (const float*)d_in[2];
  const float* bq   = (const float*)d_in[3];
  const float* Wk   = (const float*)d_in[4];
  // d_in[5] = bk: cancels in softmax
  const float* Wav  = (const float*)d_in[6];
  const float* bav  = (const float*)d_in[7];
  const float* Wfv  = (const float*)d_in[8];
  const float* bfv  = (const float*)d_in[9];
  const float* W1   = (const float*)d_in[10];
  const float* b1   = (const float*)d_in[11];
  const float* W2   = (const float*)d_in[12];
  const float* b2   = (const float*)d_in[13];
  const float* W1o  = (const float*)d_in[14];
  const float* b1o  = (const float*)d_in[15];
  const float* W2o  = (const float*)d_in[16];
  const float* b2o  = (const float*)d_in[17];
  float* out = (float*)d_out;               // [0,16384): effect; rest: attn_weights
  float* ws = (float*)d_ws;

  float* ws_w  = ws;                                        // 16384
  unsigned* ws_U2 = (unsigned*)(ws + 16384);                // 131072 uints (512KB)
  float* ws_c0 = ws + 278528;                               // 8192
  float* ws_c1 = ws + 286720;                               // 8192
  unsigned short* ws_Mbf = (unsigned short*)(ws + 294912);  // 2097152 shorts
  float* ws_W1g = ws + 1343488;                             // 163840

  hipLaunchKernelGGL(kA_prep, dim3(512), dim3(256), 0, stream,
                     feat, act, Wq, bq, Wk, Wav, bav, Wfv, bfv, W1, b1,
                     W2, b2, W1o, b1o, ws_w, ws_U2, ws_c0, ws_Mbf, ws_c1,
                     ws_W1g, out + 16384);
  hipLaunchKernelGGL(kB_main, dim3(1024), dim3(256), 0, stream,
                     feat, act, ws_w, ws_U2, ws_W1g, ws_c0, ws_Mbf, ws_c1,
                     W2o, b2o, out);
}